// Round 12
// baseline (55.848 us; speedup 1.0000x reference)
//
#include <hip/hip_runtime.h>

// E = 8*128*128 edges; MLP 16->128->256->128->(32x32 folded to 32)
// Round 12: register-resident activation chain (round-10, verified), but
// only W2s (64 KB) preloaded to LDS -> 2 blocks/CU = 4 waves/SIMD (2x TLP
// vs round 10) and halved LDS frag reads. W3s frags stream from L2 (same
// 64 KB shared by all waves). 512-thread blocks, launch_bounds(512,4)
// (cap 128 VGPR; round 11's (1024,4) forced 64 VGPR -> 45 MB spill).

typedef _Float16 f16;
typedef _Float16 f16x8 __attribute__((ext_vector_type(8)));
typedef __fp16 fp16x2 __attribute__((ext_vector_type(2)));
typedef float f32x4 __attribute__((ext_vector_type(4)));

#define OFF_W1S 0        // [8 ct][64 lane][8]  (K=16 padded: k16 = b1) natural k
#define OFF_W2S 4096     // [16 ct][4 kt][64][8]  F-permuted k
#define OFF_W3S 36864    // [8 ct][8 kt][64][8]   F-permuted k
#define OFF_W4S 69632    // [2 ct][4 kt][64][8]   F-permuted k, folded over i
#define WS_HALFS 73728

union U16x8 { struct { uint2 lo, hi; } p; f16x8 v; };
union U32x2 { fp16x2 h2[2]; uint2 u; };

// ---------------------------------------------------------------------------
// Pre-kernel. A-frag element j of lane l (u=(l>>4)&3) for (ct, kt) holds
// W[k_feat][ct*16 + (l&15)] with k_feat = kt*32 + (j>>2)*16 + u*4 + (j&3)
// (the F-labeling matching register-resident activations). W1 keeps natural
// k = u*8 + j (input from global in natural order), row 16 = b1.
// ---------------------------------------------------------------------------
__global__ void prep_kernel(const float* __restrict__ W1, const float* __restrict__ b1,
                            const float* __restrict__ W2, const float* __restrict__ W3,
                            const float* __restrict__ W4, const float* __restrict__ b4,
                            f16* __restrict__ wsh, float* __restrict__ b4r) {
  int t = blockIdx.x * 256 + threadIdx.x;
  if (t < 4096) {                       // W1s: natural k (16 + bias row + zeros)
    int j = t & 7, lq = (t >> 3) & 63, ct = t >> 9;
    int k = ((lq >> 4) & 3) * 8 + j, c = ct * 16 + (lq & 15);
    wsh[OFF_W1S + t] = (k < 16) ? (f16)W1[k * 128 + c]
                                : (k == 16 ? (f16)b1[c] : (f16)0.f);
  } else if (t < 36864) {               // W2s: F-permuted
    int s = t - 4096;
    int j = s & 7, lq = (s >> 3) & 63, kt = (s >> 9) & 3, ct = s >> 11;
    int u = (lq >> 4) & 3;
    int k = kt * 32 + (j >> 2) * 16 + u * 4 + (j & 3), c = ct * 16 + (lq & 15);
    wsh[t] = (f16)W2[k * 256 + c];
  } else if (t < 69632) {               // W3s: F-permuted
    int s = t - 36864;
    int j = s & 7, lq = (s >> 3) & 63, kt = (s >> 9) & 7, ct = s >> 12;
    int u = (lq >> 4) & 3;
    int k = kt * 32 + (j >> 2) * 16 + u * 4 + (j & 3), c = ct * 16 + (lq & 15);
    wsh[t] = (f16)W3[k * 128 + c];
  } else if (t < 73728) {               // W4s: F-permuted, folded over inner i
    int s = t - 69632;
    int j = s & 7, lq = (s >> 3) & 63, kt = (s >> 9) & 3, ct = s >> 11;
    int u = (lq >> 4) & 3;
    int k = kt * 32 + (j >> 2) * 16 + u * 4 + (j & 3), o = ct * 16 + (lq & 15);
    float a = 0.f;
#pragma unroll
    for (int i = 0; i < 32; ++i) a += W4[k * 1024 + o * 32 + i];
    wsh[t] = (f16)a;
  }
  if (t < 32) {
    float a = 0.f;
#pragma unroll
    for (int i = 0; i < 32; ++i) a += b4[t * 32 + i];
    b4r[t] = a;
  }
}

__device__ __forceinline__ uint2 relu_pack(f32x4 a) {
  U32x2 o;
  o.h2[0] = __builtin_amdgcn_cvt_pkrtz(fmaxf(a[0], 0.f), fmaxf(a[1], 0.f));
  o.h2[1] = __builtin_amdgcn_cvt_pkrtz(fmaxf(a[2], 0.f), fmaxf(a[3], 0.f));
  return o.u;
}
__device__ __forceinline__ uint2 bias_relu_pack(f32x4 a, float4 b) {
  U32x2 o;
  o.h2[0] = __builtin_amdgcn_cvt_pkrtz(fmaxf(a[0] + b.x, 0.f), fmaxf(a[1] + b.y, 0.f));
  o.h2[1] = __builtin_amdgcn_cvt_pkrtz(fmaxf(a[2] + b.z, 0.f), fmaxf(a[3] + b.w, 0.f));
  return o.u;
}

// ---------------------------------------------------------------------------
// Fused MLP: 512 threads (8 waves), 2 blocks/CU. Each wave owns 32 edges
// (2 16-edge tiles; weight frags read once, used twice). Activations live
// in VGPRs end-to-end; one barrier total (after W2s preload). W2 frags from
// LDS; W1/W3/W4 frags from L2 (workspace, shared across all blocks).
// ---------------------------------------------------------------------------
__global__ __launch_bounds__(512, 4) void mlp_mfma_kernel(
    const float* __restrict__ e_vw, const float* __restrict__ h_w,
    const float* __restrict__ b2, const float* __restrict__ b3,
    const f16* __restrict__ wsh, const float* __restrict__ b4r,
    float* __restrict__ out) {
  __shared__ f16 WT[32768];   // 64 KB: W2s'

  const int tid = threadIdx.x;
  const int l = tid & 63, w = tid >> 6;
  const int e0 = l & 15, u = l >> 4;
  const size_t base = (size_t)blockIdx.x * 256 + (size_t)w * 32;

  const f16x8* wp1 = (const f16x8*)(wsh + OFF_W1S);
  const f16x8* wp3 = (const f16x8*)(wsh + OFF_W3S);
  const f16x8* wp4 = (const f16x8*)(wsh + OFF_W4S);

  // ---- stage inputs (global; overlaps preload) ----
  U16x8 xin[2];
#pragma unroll
  for (int ti = 0; ti < 2; ++ti) {
    if (u < 2) {
      const float* pe = e_vw + (base + ti * 16 + e0) * 16 + u * 8;
      float4 v0 = *reinterpret_cast<const float4*>(pe);
      float4 v1 = *reinterpret_cast<const float4*>(pe + 4);
      U32x2 c0, c1;
      c0.h2[0] = __builtin_amdgcn_cvt_pkrtz(v0.x, v0.y);
      c0.h2[1] = __builtin_amdgcn_cvt_pkrtz(v0.z, v0.w);
      c1.h2[0] = __builtin_amdgcn_cvt_pkrtz(v1.x, v1.y);
      c1.h2[1] = __builtin_amdgcn_cvt_pkrtz(v1.z, v1.w);
      xin[ti].p.lo = c0.u; xin[ti].p.hi = c1.u;
    } else {
      xin[ti].p.lo.x = (u == 2) ? 0x00003C00u : 0u;  // k=16 -> 1.0 (bias slot)
      xin[ti].p.lo.y = 0u; xin[ti].p.hi.x = 0u; xin[ti].p.hi.y = 0u;
    }
  }

  // ---- preload W2s' into LDS (65536 B, 8 float4 per thread) ----
  {
    const float4* src = (const float4*)(wsh + OFF_W2S);
    float4* dst = (float4*)WT;
#pragma unroll
    for (int i = 0; i < 8; ++i) dst[tid + i * 512] = src[tid + i * 512];
  }
  __syncthreads();

  // ---- L1: 16 -> 128 (bias folded in K-pad; W1 frags from L2) ----
  U16x8 x1[2][4];
  const f32x4 z4 = {0.f, 0.f, 0.f, 0.f};
#pragma unroll
  for (int ct = 0; ct < 8; ++ct) {
    f16x8 wf = wp1[ct * 64 + l];
    f32x4 a0 = __builtin_amdgcn_mfma_f32_16x16x32_f16(wf, xin[0].v, z4, 0, 0, 0);
    f32x4 a1 = __builtin_amdgcn_mfma_f32_16x16x32_f16(wf, xin[1].v, z4, 0, 0, 0);
    uint2 d0 = relu_pack(a0), d1 = relu_pack(a1);
    if (ct & 1) { x1[0][ct >> 1].p.hi = d0; x1[1][ct >> 1].p.hi = d1; }
    else        { x1[0][ct >> 1].p.lo = d0; x1[1][ct >> 1].p.lo = d1; }
  }

  // ---- L2: 128 -> 256 (weights from LDS; B-frag = x1[kt] directly) ----
  U16x8 x2[2][8];
#pragma unroll
  for (int ct = 0; ct < 16; ++ct) {
    f32x4 a0 = z4, a1 = z4;
#pragma unroll
    for (int kt = 0; kt < 4; ++kt) {
      f16x8 wf = *(const f16x8*)(WT + ((ct * 4 + kt) * 64 + l) * 8);
      a0 = __builtin_amdgcn_mfma_f32_16x16x32_f16(wf, x1[0][kt].v, a0, 0, 0, 0);
      a1 = __builtin_amdgcn_mfma_f32_16x16x32_f16(wf, x1[1][kt].v, a1, 0, 0, 0);
    }
    float4 bb = *reinterpret_cast<const float4*>(b2 + ct * 16 + u * 4);
    uint2 d0 = bias_relu_pack(a0, bb), d1 = bias_relu_pack(a1, bb);
    if (ct & 1) { x2[0][ct >> 1].p.hi = d0; x2[1][ct >> 1].p.hi = d1; }
    else        { x2[0][ct >> 1].p.lo = d0; x2[1][ct >> 1].p.lo = d1; }
  }

  // ---- L3: 256 -> 128 (weights stream from L2; same 64 KB for all waves) --
  U16x8 x3[2][4];
#pragma unroll
  for (int ct = 0; ct < 8; ++ct) {
    f32x4 a0 = z4, a1 = z4;
#pragma unroll
    for (int kt = 0; kt < 8; ++kt) {
      f16x8 wf = wp3[(ct * 8 + kt) * 64 + l];
      a0 = __builtin_amdgcn_mfma_f32_16x16x32_f16(wf, x2[0][kt].v, a0, 0, 0, 0);
      a1 = __builtin_amdgcn_mfma_f32_16x16x32_f16(wf, x2[1][kt].v, a1, 0, 0, 0);
    }
    float4 bb = *reinterpret_cast<const float4*>(b3 + ct * 16 + u * 4);
    uint2 d0 = bias_relu_pack(a0, bb), d1 = bias_relu_pack(a1, bb);
    if (ct & 1) { x3[0][ct >> 1].p.hi = d0; x3[1][ct >> 1].p.hi = d1; }
    else        { x3[0][ct >> 1].p.lo = d0; x3[1][ct >> 1].p.lo = d1; }
  }

  // ---- L4: 128 -> 32 (folded), scale by s_e, coalesced float4 store ----
#pragma unroll
  for (int ti = 0; ti < 2; ++ti) {
    size_t e = base + ti * 16 + e0;
    float s = h_w[(e >> 7) * 32 + ((e & 127) >> 2)];
#pragma unroll
    for (int ct = 0; ct < 2; ++ct) {
      f32x4 acc = z4;
#pragma unroll
      for (int kt = 0; kt < 4; ++kt)
        acc = __builtin_amdgcn_mfma_f32_16x16x32_f16(wp4[(ct * 4 + kt) * 64 + l],
                                                     x3[ti][kt].v, acc, 0, 0, 0);
      float4 bb = *reinterpret_cast<const float4*>(b4r + ct * 16 + u * 4);
      float4 st;
      st.x = s * (acc[0] + bb.x); st.y = s * (acc[1] + bb.y);
      st.z = s * (acc[2] + bb.z); st.w = s * (acc[3] + bb.w);
      *reinterpret_cast<float4*>(out + e * 32 + ct * 16 + u * 4) = st;
    }
  }
}

// ---------------------------------------------------------------------------
extern "C" void kernel_launch(void* const* d_in, const int* in_sizes, int n_in,
                              void* d_out, int out_size, void* d_ws, size_t ws_size,
                              hipStream_t stream) {
  // inputs: h_v, h_w, e_vw, W1, b1, W2, b2, W3, b3, W4, b4
  const float* h_w  = (const float*)d_in[1];
  const float* e_vw = (const float*)d_in[2];
  const float* W1   = (const float*)d_in[3];
  const float* b1   = (const float*)d_in[4];
  const float* W2   = (const float*)d_in[5];
  const float* b2   = (const float*)d_in[6];
  const float* W3   = (const float*)d_in[7];
  const float* b3   = (const float*)d_in[8];
  const float* W4   = (const float*)d_in[9];
  const float* b4   = (const float*)d_in[10];
  float* out = (float*)d_out;

  f16*   wsh = (f16*)d_ws;
  float* b4r = (float*)((char*)d_ws + (size_t)WS_HALFS * 2);

  const int E = in_sizes[2] / 16;       // 131072
  const int blocks = E / 256;           // 512 (8 waves x 32 edges each)

  hipLaunchKernelGGL(prep_kernel, dim3(288), dim3(256), 0, stream,
                     W1, b1, W2, W3, W4, b4, wsh, b4r);
  hipLaunchKernelGGL(mlp_mfma_kernel, dim3(blocks), dim3(512), 0, stream,
                     e_vw, h_w, b2, b3, wsh, b4r, out);
}

// Round 13
// 51.851 us; speedup vs baseline: 1.0771x; 1.0771x over previous
//
#include <hip/hip_runtime.h>

// E = 8*128*128 edges; MLP 16->128->256->128->(32x32 folded to 32)
// Round 13: register-resident chain, ONE 16-edge tile per wave (halves live
// VGPRs to ~90 so the 128-cap of 2-blocks/CU occupancy actually fits).
// W2s (64 KB) in LDS; W1/W3/W4 frags from L2. launch_bounds(512,2):
// empirically 2nd arg acts like CUDA min-blocks/CU -> 2 blocks x 8 waves
// = 4 waves/SIMD, VGPR cap 128. (512,4)/(1024,4) forced 64 VGPR + 57 MB
// spill (rounds 11/12) -- never again.

typedef _Float16 f16;
typedef _Float16 f16x8 __attribute__((ext_vector_type(8)));
typedef __fp16 fp16x2 __attribute__((ext_vector_type(2)));
typedef float f32x4 __attribute__((ext_vector_type(4)));

#define OFF_W1S 0        // [8 ct][64 lane][8]  (K=16 padded: k16 = b1) natural k
#define OFF_W2S 4096     // [16 ct][4 kt][64][8]  F-permuted k
#define OFF_W3S 36864    // [8 ct][8 kt][64][8]   F-permuted k
#define OFF_W4S 69632    // [2 ct][4 kt][64][8]   F-permuted k, folded over i
#define WS_HALFS 73728

union U16x8 { struct { uint2 lo, hi; } p; f16x8 v; };
union U32x2 { fp16x2 h2[2]; uint2 u; };

// ---------------------------------------------------------------------------
// Pre-kernel. A-frag element j of lane l (u=(l>>4)&3) for (ct, kt) holds
// W[k_feat][ct*16 + (l&15)] with k_feat = kt*32 + (j>>2)*16 + u*4 + (j&3)
// (the F-labeling matching register-resident activations). W1 keeps natural
// k = u*8 + j (input from global in natural order), row 16 = b1.
// ---------------------------------------------------------------------------
__global__ void prep_kernel(const float* __restrict__ W1, const float* __restrict__ b1,
                            const float* __restrict__ W2, const float* __restrict__ W3,
                            const float* __restrict__ W4, const float* __restrict__ b4,
                            f16* __restrict__ wsh, float* __restrict__ b4r) {
  int t = blockIdx.x * 256 + threadIdx.x;
  if (t < 4096) {                       // W1s: natural k (16 + bias row + zeros)
    int j = t & 7, lq = (t >> 3) & 63, ct = t >> 9;
    int k = ((lq >> 4) & 3) * 8 + j, c = ct * 16 + (lq & 15);
    wsh[OFF_W1S + t] = (k < 16) ? (f16)W1[k * 128 + c]
                                : (k == 16 ? (f16)b1[c] : (f16)0.f);
  } else if (t < 36864) {               // W2s: F-permuted
    int s = t - 4096;
    int j = s & 7, lq = (s >> 3) & 63, kt = (s >> 9) & 3, ct = s >> 11;
    int u = (lq >> 4) & 3;
    int k = kt * 32 + (j >> 2) * 16 + u * 4 + (j & 3), c = ct * 16 + (lq & 15);
    wsh[t] = (f16)W2[k * 256 + c];
  } else if (t < 69632) {               // W3s: F-permuted
    int s = t - 36864;
    int j = s & 7, lq = (s >> 3) & 63, kt = (s >> 9) & 7, ct = s >> 12;
    int u = (lq >> 4) & 3;
    int k = kt * 32 + (j >> 2) * 16 + u * 4 + (j & 3), c = ct * 16 + (lq & 15);
    wsh[t] = (f16)W3[k * 128 + c];
  } else if (t < 73728) {               // W4s: F-permuted, folded over inner i
    int s = t - 69632;
    int j = s & 7, lq = (s >> 3) & 63, kt = (s >> 9) & 3, ct = s >> 11;
    int u = (lq >> 4) & 3;
    int k = kt * 32 + (j >> 2) * 16 + u * 4 + (j & 3), o = ct * 16 + (lq & 15);
    float a = 0.f;
#pragma unroll
    for (int i = 0; i < 32; ++i) a += W4[k * 1024 + o * 32 + i];
    wsh[t] = (f16)a;
  }
  if (t < 32) {
    float a = 0.f;
#pragma unroll
    for (int i = 0; i < 32; ++i) a += b4[t * 32 + i];
    b4r[t] = a;
  }
}

__device__ __forceinline__ uint2 relu_pack(f32x4 a) {
  U32x2 o;
  o.h2[0] = __builtin_amdgcn_cvt_pkrtz(fmaxf(a[0], 0.f), fmaxf(a[1], 0.f));
  o.h2[1] = __builtin_amdgcn_cvt_pkrtz(fmaxf(a[2], 0.f), fmaxf(a[3], 0.f));
  return o.u;
}
__device__ __forceinline__ uint2 bias_relu_pack(f32x4 a, float4 b) {
  U32x2 o;
  o.h2[0] = __builtin_amdgcn_cvt_pkrtz(fmaxf(a[0] + b.x, 0.f), fmaxf(a[1] + b.y, 0.f));
  o.h2[1] = __builtin_amdgcn_cvt_pkrtz(fmaxf(a[2] + b.z, 0.f), fmaxf(a[3] + b.w, 0.f));
  return o.u;
}

// ---------------------------------------------------------------------------
// Fused MLP: 512 threads (8 waves), each wave owns ONE 16-edge tile.
// 1024 blocks. Activations in VGPRs end-to-end; one barrier (W2s preload).
// W2 frags from LDS; W1/W3/W4 frags from L2 (shared by all waves).
// ---------------------------------------------------------------------------
__global__ __launch_bounds__(512, 2) void mlp_mfma_kernel(
    const float* __restrict__ e_vw, const float* __restrict__ h_w,
    const float* __restrict__ b2, const float* __restrict__ b3,
    const f16* __restrict__ wsh, const float* __restrict__ b4r,
    float* __restrict__ out) {
  __shared__ f16 WT[32768];   // 64 KB: W2s'

  const int tid = threadIdx.x;
  const int l = tid & 63, w = tid >> 6;
  const int e0 = l & 15, u = l >> 4;
  const size_t base = (size_t)blockIdx.x * 128 + (size_t)w * 16;

  const f16x8* wp1 = (const f16x8*)(wsh + OFF_W1S);
  const f16x8* wp3 = (const f16x8*)(wsh + OFF_W3S);
  const f16x8* wp4 = (const f16x8*)(wsh + OFF_W4S);

  // ---- stage input (global; overlaps preload) ----
  U16x8 xin;
  if (u < 2) {
    const float* pe = e_vw + (base + e0) * 16 + u * 8;
    float4 v0 = *reinterpret_cast<const float4*>(pe);
    float4 v1 = *reinterpret_cast<const float4*>(pe + 4);
    U32x2 c0, c1;
    c0.h2[0] = __builtin_amdgcn_cvt_pkrtz(v0.x, v0.y);
    c0.h2[1] = __builtin_amdgcn_cvt_pkrtz(v0.z, v0.w);
    c1.h2[0] = __builtin_amdgcn_cvt_pkrtz(v1.x, v1.y);
    c1.h2[1] = __builtin_amdgcn_cvt_pkrtz(v1.z, v1.w);
    xin.p.lo = c0.u; xin.p.hi = c1.u;
  } else {
    xin.p.lo.x = (u == 2) ? 0x00003C00u : 0u;  // k=16 -> 1.0 (bias slot)
    xin.p.lo.y = 0u; xin.p.hi.x = 0u; xin.p.hi.y = 0u;
  }

  // ---- preload W2s' into LDS (65536 B, 8 float4 per thread) ----
  {
    const float4* src = (const float4*)(wsh + OFF_W2S);
    float4* dst = (float4*)WT;
#pragma unroll
    for (int i = 0; i < 8; ++i) dst[tid + i * 512] = src[tid + i * 512];
  }
  __syncthreads();

  // ---- L1: 16 -> 128 (bias folded in K-pad; W1 frags from L2) ----
  U16x8 x1[4];
  const f32x4 z4 = {0.f, 0.f, 0.f, 0.f};
#pragma unroll
  for (int ct = 0; ct < 8; ++ct) {
    f16x8 wf = wp1[ct * 64 + l];
    f32x4 a0 = __builtin_amdgcn_mfma_f32_16x16x32_f16(wf, xin.v, z4, 0, 0, 0);
    uint2 d0 = relu_pack(a0);
    if (ct & 1) x1[ct >> 1].p.hi = d0; else x1[ct >> 1].p.lo = d0;
  }

  // ---- L2: 128 -> 256 (weights from LDS; B-frag = x1[kt] directly) ----
  U16x8 x2[8];
#pragma unroll
  for (int ct = 0; ct < 16; ++ct) {
    f32x4 a0 = z4;
#pragma unroll
    for (int kt = 0; kt < 4; ++kt) {
      f16x8 wf = *(const f16x8*)(WT + ((ct * 4 + kt) * 64 + l) * 8);
      a0 = __builtin_amdgcn_mfma_f32_16x16x32_f16(wf, x1[kt].v, a0, 0, 0, 0);
    }
    float4 bb = *reinterpret_cast<const float4*>(b2 + ct * 16 + u * 4);
    uint2 d0 = bias_relu_pack(a0, bb);
    if (ct & 1) x2[ct >> 1].p.hi = d0; else x2[ct >> 1].p.lo = d0;
  }

  // ---- L3: 256 -> 128 (weights stream from L2; same 64 KB for all waves) --
  U16x8 x3[4];
#pragma unroll
  for (int ct = 0; ct < 8; ++ct) {
    f32x4 a0 = z4;
#pragma unroll
    for (int kt = 0; kt < 8; ++kt) {
      f16x8 wf = wp3[(ct * 8 + kt) * 64 + l];
      a0 = __builtin_amdgcn_mfma_f32_16x16x32_f16(wf, x2[kt].v, a0, 0, 0, 0);
    }
    float4 bb = *reinterpret_cast<const float4*>(b3 + ct * 16 + u * 4);
    uint2 d0 = bias_relu_pack(a0, bb);
    if (ct & 1) x3[ct >> 1].p.hi = d0; else x3[ct >> 1].p.lo = d0;
  }

  // ---- L4: 128 -> 32 (folded), scale by s_e, coalesced float4 store ----
  {
    size_t e = base + e0;
    float s = h_w[(e >> 7) * 32 + ((e & 127) >> 2)];
#pragma unroll
    for (int ct = 0; ct < 2; ++ct) {
      f32x4 acc = z4;
#pragma unroll
      for (int kt = 0; kt < 4; ++kt)
        acc = __builtin_amdgcn_mfma_f32_16x16x32_f16(wp4[(ct * 4 + kt) * 64 + l],
                                                     x3[kt].v, acc, 0, 0, 0);
      float4 bb = *reinterpret_cast<const float4*>(b4r + ct * 16 + u * 4);
      float4 st;
      st.x = s * (acc[0] + bb.x); st.y = s * (acc[1] + bb.y);
      st.z = s * (acc[2] + bb.z); st.w = s * (acc[3] + bb.w);
      *reinterpret_cast<float4*>(out + e * 32 + ct * 16 + u * 4) = st;
    }
  }
}

// ---------------------------------------------------------------------------
extern "C" void kernel_launch(void* const* d_in, const int* in_sizes, int n_in,
                              void* d_out, int out_size, void* d_ws, size_t ws_size,
                              hipStream_t stream) {
  // inputs: h_v, h_w, e_vw, W1, b1, W2, b2, W3, b3, W4, b4
  const float* h_w  = (const float*)d_in[1];
  const float* e_vw = (const float*)d_in[2];
  const float* W1   = (const float*)d_in[3];
  const float* b1   = (const float*)d_in[4];
  const float* W2   = (const float*)d_in[5];
  const float* b2   = (const float*)d_in[6];
  const float* W3   = (const float*)d_in[7];
  const float* b3   = (const float*)d_in[8];
  const float* W4   = (const float*)d_in[9];
  const float* b4   = (const float*)d_in[10];
  float* out = (float*)d_out;

  f16*   wsh = (f16*)d_ws;
  float* b4r = (float*)((char*)d_ws + (size_t)WS_HALFS * 2);

  const int E = in_sizes[2] / 16;       // 131072
  const int blocks = E / 128;           // 1024 (8 waves x 16 edges each)

  hipLaunchKernelGGL(prep_kernel, dim3(288), dim3(256), 0, stream,
                     W1, b1, W2, W3, W4, b4, wsh, b4r);
  hipLaunchKernelGGL(mlp_mfma_kernel, dim3(blocks), dim3(512), 0, stream,
                     e_vw, h_w, b2, b3, wsh, b4r, out);
}

// Round 14
// 39.190 us; speedup vs baseline: 1.4250x; 1.3231x over previous
//
#include <hip/hip_runtime.h>

// E = 8*128*128 edges; MLP 16->128->256->128->(32x32 folded to 32)
// Round 14: R10's register-resident chain + 2-tile amortization + ALL weight
// tables in LDS (144 KB), with a CU-wide 1024-thread block and (1024,1):
// 16 waves = 4 waves/SIMD at 1 block/CU (R11's idea minus its launch-bounds
// trap: empirically 2nd arg = min blocks/CU; (1024,4)->64 VGPR cap+spill,
// (1024,1)->128 cap). Grid 256 = exactly 1 block/CU, single dispatch round.

typedef _Float16 f16;
typedef _Float16 f16x8 __attribute__((ext_vector_type(8)));
typedef __fp16 fp16x2 __attribute__((ext_vector_type(2)));
typedef float f32x4 __attribute__((ext_vector_type(4)));

#define OFF_W1S 0        // [8 ct][64 lane][8]  (K=16 padded: k16 = b1) natural k
#define OFF_W2S 4096     // [16 ct][4 kt][64][8]  F-permuted k
#define OFF_W3S 36864    // [8 ct][8 kt][64][8]   F-permuted k
#define OFF_W4S 69632    // [2 ct][4 kt][64][8]   F-permuted k, folded over i
#define WS_HALFS 73728   // 144 KB total

union U16x8 { struct { uint2 lo, hi; } p; f16x8 v; };
union U32x2 { fp16x2 h2[2]; uint2 u; };

// ---------------------------------------------------------------------------
// Pre-kernel. A-frag element j of lane l (u=(l>>4)&3) for (ct, kt) holds
// W[k_feat][ct*16 + (l&15)] with k_feat = kt*32 + (j>>2)*16 + u*4 + (j&3)
// (the F-labeling matching register-resident activations). W1 keeps natural
// k = u*8 + j (input from global in natural order), row 16 = b1.
// ---------------------------------------------------------------------------
__global__ void prep_kernel(const float* __restrict__ W1, const float* __restrict__ b1,
                            const float* __restrict__ W2, const float* __restrict__ W3,
                            const float* __restrict__ W4, const float* __restrict__ b4,
                            f16* __restrict__ wsh, float* __restrict__ b4r) {
  int t = blockIdx.x * 256 + threadIdx.x;
  if (t < 4096) {                       // W1s: natural k (16 + bias row + zeros)
    int j = t & 7, lq = (t >> 3) & 63, ct = t >> 9;
    int k = ((lq >> 4) & 3) * 8 + j, c = ct * 16 + (lq & 15);
    wsh[OFF_W1S + t] = (k < 16) ? (f16)W1[k * 128 + c]
                                : (k == 16 ? (f16)b1[c] : (f16)0.f);
  } else if (t < 36864) {               // W2s: F-permuted
    int s = t - 4096;
    int j = s & 7, lq = (s >> 3) & 63, kt = (s >> 9) & 3, ct = s >> 11;
    int u = (lq >> 4) & 3;
    int k = kt * 32 + (j >> 2) * 16 + u * 4 + (j & 3), c = ct * 16 + (lq & 15);
    wsh[t] = (f16)W2[k * 256 + c];
  } else if (t < 69632) {               // W3s: F-permuted
    int s = t - 36864;
    int j = s & 7, lq = (s >> 3) & 63, kt = (s >> 9) & 7, ct = s >> 12;
    int u = (lq >> 4) & 3;
    int k = kt * 32 + (j >> 2) * 16 + u * 4 + (j & 3), c = ct * 16 + (lq & 15);
    wsh[t] = (f16)W3[k * 128 + c];
  } else if (t < 73728) {               // W4s: F-permuted, folded over inner i
    int s = t - 69632;
    int j = s & 7, lq = (s >> 3) & 63, kt = (s >> 9) & 3, ct = s >> 11;
    int u = (lq >> 4) & 3;
    int k = kt * 32 + (j >> 2) * 16 + u * 4 + (j & 3), o = ct * 16 + (lq & 15);
    float a = 0.f;
#pragma unroll
    for (int i = 0; i < 32; ++i) a += W4[k * 1024 + o * 32 + i];
    wsh[t] = (f16)a;
  }
  if (t < 32) {
    float a = 0.f;
#pragma unroll
    for (int i = 0; i < 32; ++i) a += b4[t * 32 + i];
    b4r[t] = a;
  }
}

__device__ __forceinline__ uint2 relu_pack(f32x4 a) {
  U32x2 o;
  o.h2[0] = __builtin_amdgcn_cvt_pkrtz(fmaxf(a[0], 0.f), fmaxf(a[1], 0.f));
  o.h2[1] = __builtin_amdgcn_cvt_pkrtz(fmaxf(a[2], 0.f), fmaxf(a[3], 0.f));
  return o.u;
}
__device__ __forceinline__ uint2 bias_relu_pack(f32x4 a, float4 b) {
  U32x2 o;
  o.h2[0] = __builtin_amdgcn_cvt_pkrtz(fmaxf(a[0] + b.x, 0.f), fmaxf(a[1] + b.y, 0.f));
  o.h2[1] = __builtin_amdgcn_cvt_pkrtz(fmaxf(a[2] + b.z, 0.f), fmaxf(a[3] + b.w, 0.f));
  return o.u;
}

// ---------------------------------------------------------------------------
// Fused MLP: 1024 threads (16 waves), 1 block/CU, each wave owns 32 edges
// (2 16-edge tiles; every weight frag loaded once, used twice). Activations
// in VGPRs end-to-end; one barrier (weight preload). All frags from LDS.
// ---------------------------------------------------------------------------
__global__ __launch_bounds__(1024, 1) void mlp_mfma_kernel(
    const float* __restrict__ e_vw, const float* __restrict__ h_w,
    const float* __restrict__ b2, const float* __restrict__ b3,
    const f16* __restrict__ wsh, const float* __restrict__ b4r,
    float* __restrict__ out) {
  __shared__ f16 WT[WS_HALFS];   // 144 KB: full pre-swizzled weight table

  const int tid = threadIdx.x;
  const int l = tid & 63, w = tid >> 6;
  const int e0 = l & 15, u = l >> 4;
  const size_t base = (size_t)blockIdx.x * 512 + (size_t)w * 32;

  // ---- stage inputs (global; overlaps preload) ----
  U16x8 xin[2];
#pragma unroll
  for (int ti = 0; ti < 2; ++ti) {
    if (u < 2) {
      const float* pe = e_vw + (base + ti * 16 + e0) * 16 + u * 8;
      float4 v0 = *reinterpret_cast<const float4*>(pe);
      float4 v1 = *reinterpret_cast<const float4*>(pe + 4);
      U32x2 c0, c1;
      c0.h2[0] = __builtin_amdgcn_cvt_pkrtz(v0.x, v0.y);
      c0.h2[1] = __builtin_amdgcn_cvt_pkrtz(v0.z, v0.w);
      c1.h2[0] = __builtin_amdgcn_cvt_pkrtz(v1.x, v1.y);
      c1.h2[1] = __builtin_amdgcn_cvt_pkrtz(v1.z, v1.w);
      xin[ti].p.lo = c0.u; xin[ti].p.hi = c1.u;
    } else {
      xin[ti].p.lo.x = (u == 2) ? 0x00003C00u : 0u;  // k=16 -> 1.0 (bias slot)
      xin[ti].p.lo.y = 0u; xin[ti].p.hi.x = 0u; xin[ti].p.hi.y = 0u;
    }
  }

  // ---- preload full weight table into LDS (147456 B = 9 float4/thread) ----
  {
    const float4* src = (const float4*)wsh;
    float4* dst = (float4*)WT;
#pragma unroll
    for (int i = 0; i < 9; ++i) dst[tid + i * 1024] = src[tid + i * 1024];
  }
  __syncthreads();

  // ---- L1: 16 -> 128 (bias folded in K-pad) ----
  U16x8 x1[2][4];
  const f32x4 z4 = {0.f, 0.f, 0.f, 0.f};
#pragma unroll
  for (int ct = 0; ct < 8; ++ct) {
    f16x8 wf = *(const f16x8*)(WT + OFF_W1S + (ct * 64 + l) * 8);
    f32x4 a0 = __builtin_amdgcn_mfma_f32_16x16x32_f16(wf, xin[0].v, z4, 0, 0, 0);
    f32x4 a1 = __builtin_amdgcn_mfma_f32_16x16x32_f16(wf, xin[1].v, z4, 0, 0, 0);
    uint2 d0 = relu_pack(a0), d1 = relu_pack(a1);
    if (ct & 1) { x1[0][ct >> 1].p.hi = d0; x1[1][ct >> 1].p.hi = d1; }
    else        { x1[0][ct >> 1].p.lo = d0; x1[1][ct >> 1].p.lo = d1; }
  }

  // ---- L2: 128 -> 256 (B-frag = x1[kt] directly) ----
  U16x8 x2[2][8];
#pragma unroll
  for (int ct = 0; ct < 16; ++ct) {
    f32x4 a0 = z4, a1 = z4;
#pragma unroll
    for (int kt = 0; kt < 4; ++kt) {
      f16x8 wf = *(const f16x8*)(WT + OFF_W2S + ((ct * 4 + kt) * 64 + l) * 8);
      a0 = __builtin_amdgcn_mfma_f32_16x16x32_f16(wf, x1[0][kt].v, a0, 0, 0, 0);
      a1 = __builtin_amdgcn_mfma_f32_16x16x32_f16(wf, x1[1][kt].v, a1, 0, 0, 0);
    }
    float4 bb = *reinterpret_cast<const float4*>(b2 + ct * 16 + u * 4);
    uint2 d0 = bias_relu_pack(a0, bb), d1 = bias_relu_pack(a1, bb);
    if (ct & 1) { x2[0][ct >> 1].p.hi = d0; x2[1][ct >> 1].p.hi = d1; }
    else        { x2[0][ct >> 1].p.lo = d0; x2[1][ct >> 1].p.lo = d1; }
  }

  // ---- L3: 256 -> 128 ----
  U16x8 x3[2][4];
#pragma unroll
  for (int ct = 0; ct < 8; ++ct) {
    f32x4 a0 = z4, a1 = z4;
#pragma unroll
    for (int kt = 0; kt < 8; ++kt) {
      f16x8 wf = *(const f16x8*)(WT + OFF_W3S + ((ct * 8 + kt) * 64 + l) * 8);
      a0 = __builtin_amdgcn_mfma_f32_16x16x32_f16(wf, x2[0][kt].v, a0, 0, 0, 0);
      a1 = __builtin_amdgcn_mfma_f32_16x16x32_f16(wf, x2[1][kt].v, a1, 0, 0, 0);
    }
    float4 bb = *reinterpret_cast<const float4*>(b3 + ct * 16 + u * 4);
    uint2 d0 = bias_relu_pack(a0, bb), d1 = bias_relu_pack(a1, bb);
    if (ct & 1) { x3[0][ct >> 1].p.hi = d0; x3[1][ct >> 1].p.hi = d1; }
    else        { x3[0][ct >> 1].p.lo = d0; x3[1][ct >> 1].p.lo = d1; }
  }

  // ---- L4: 128 -> 32 (folded), scale by s_e, coalesced float4 store ----
#pragma unroll
  for (int ti = 0; ti < 2; ++ti) {
    size_t e = base + ti * 16 + e0;
    float s = h_w[(e >> 7) * 32 + ((e & 127) >> 2)];
#pragma unroll
    for (int ct = 0; ct < 2; ++ct) {
      f32x4 acc = z4;
#pragma unroll
      for (int kt = 0; kt < 4; ++kt) {
        f16x8 wf = *(const f16x8*)(WT + OFF_W4S + ((ct * 4 + kt) * 64 + l) * 8);
        acc = __builtin_amdgcn_mfma_f32_16x16x32_f16(wf, x3[ti][kt].v, acc, 0, 0, 0);
      }
      float4 bb = *reinterpret_cast<const float4*>(b4r + ct * 16 + u * 4);
      float4 st;
      st.x = s * (acc[0] + bb.x); st.y = s * (acc[1] + bb.y);
      st.z = s * (acc[2] + bb.z); st.w = s * (acc[3] + bb.w);
      *reinterpret_cast<float4*>(out + e * 32 + ct * 16 + u * 4) = st;
    }
  }
}

// ---------------------------------------------------------------------------
extern "C" void kernel_launch(void* const* d_in, const int* in_sizes, int n_in,
                              void* d_out, int out_size, void* d_ws, size_t ws_size,
                              hipStream_t stream) {
  // inputs: h_v, h_w, e_vw, W1, b1, W2, b2, W3, b3, W4, b4
  const float* h_w  = (const float*)d_in[1];
  const float* e_vw = (const float*)d_in[2];
  const float* W1   = (const float*)d_in[3];
  const float* b1   = (const float*)d_in[4];
  const float* W2   = (const float*)d_in[5];
  const float* b2   = (const float*)d_in[6];
  const float* W3   = (const float*)d_in[7];
  const float* b3   = (const float*)d_in[8];
  const float* W4   = (const float*)d_in[9];
  const float* b4   = (const float*)d_in[10];
  float* out = (float*)d_out;

  f16*   wsh = (f16*)d_ws;
  float* b4r = (float*)((char*)d_ws + (size_t)WS_HALFS * 2);

  const int E = in_sizes[2] / 16;       // 131072
  const int blocks = E / 512;           // 256 = 1 block per CU

  hipLaunchKernelGGL(prep_kernel, dim3(288), dim3(256), 0, stream,
                     W1, b1, W2, W3, W4, b4, wsh, b4r);
  hipLaunchKernelGGL(mlp_mfma_kernel, dim3(blocks), dim3(1024), 0, stream,
                     e_vw, h_w, b2, b3, wsh, b4r, out);
}

// Round 17
// 35.241 us; speedup vs baseline: 1.5848x; 1.1121x over previous
//
#include <hip/hip_runtime.h>

// E = 8*128*128 edges; MLP 16->128->256->128->(32x32 folded to 32)
// Round 17 = round 15 resubmit x2 (container died pre-delivery both times).
// R10 chain (proven 30.0us, ~124 live VGPR, no spill) at HIGHER occupancy:
// 768-thread block (12 waves) = 3 waves/SIMD at 1 block/CU (VGPR cap ~170 >
// 124 live). 1024-thr blocks are toolchain-clamped to 64 arch-VGPRs
// (R11/R14 spills); 512-thr (512,2) = 2 waves/SIMD (R10). 768 is the
// untested middle. Grid 342 with per-wave guard (E not divisible by 384).

typedef _Float16 f16;
typedef _Float16 f16x8 __attribute__((ext_vector_type(8)));
typedef __fp16 fp16x2 __attribute__((ext_vector_type(2)));
typedef float f32x4 __attribute__((ext_vector_type(4)));

#define OFF_W1S 0        // [8 ct][64 lane][8]  (K=16 padded: k16 = b1) natural k
#define OFF_W2S 4096     // [16 ct][4 kt][64][8]  F-permuted k
#define OFF_W3S 36864    // [8 ct][8 kt][64][8]   F-permuted k
#define OFF_W4S 69632    // [2 ct][4 kt][64][8]   F-permuted k, folded over i
#define WS_HALFS 73728

union U16x8 { struct { uint2 lo, hi; } p; f16x8 v; };
union U32x2 { fp16x2 h2[2]; uint2 u; };

// ---------------------------------------------------------------------------
// Pre-kernel. A-frag element j of lane l (u=(l>>4)&3) for (ct, kt) holds
// W[k_feat][ct*16 + (l&15)] with k_feat = kt*32 + (j>>2)*16 + u*4 + (j&3)
// (the F-labeling matching register-resident activations). W1 keeps natural
// k = u*8 + j (input from global in natural order), row 16 = b1.
// ---------------------------------------------------------------------------
__global__ void prep_kernel(const float* __restrict__ W1, const float* __restrict__ b1,
                            const float* __restrict__ W2, const float* __restrict__ W3,
                            const float* __restrict__ W4, const float* __restrict__ b4,
                            f16* __restrict__ wsh, float* __restrict__ b4r) {
  int t = blockIdx.x * 256 + threadIdx.x;
  if (t < 4096) {                       // W1s: natural k (16 + bias row + zeros)
    int j = t & 7, lq = (t >> 3) & 63, ct = t >> 9;
    int k = ((lq >> 4) & 3) * 8 + j, c = ct * 16 + (lq & 15);
    wsh[OFF_W1S + t] = (k < 16) ? (f16)W1[k * 128 + c]
                                : (k == 16 ? (f16)b1[c] : (f16)0.f);
  } else if (t < 36864) {               // W2s: F-permuted
    int s = t - 4096;
    int j = s & 7, lq = (s >> 3) & 63, kt = (s >> 9) & 3, ct = s >> 11;
    int u = (lq >> 4) & 3;
    int k = kt * 32 + (j >> 2) * 16 + u * 4 + (j & 3), c = ct * 16 + (lq & 15);
    wsh[t] = (f16)W2[k * 256 + c];
  } else if (t < 69632) {               // W3s: F-permuted
    int s = t - 36864;
    int j = s & 7, lq = (s >> 3) & 63, kt = (s >> 9) & 7, ct = s >> 12;
    int u = (lq >> 4) & 3;
    int k = kt * 32 + (j >> 2) * 16 + u * 4 + (j & 3), c = ct * 16 + (lq & 15);
    wsh[t] = (f16)W3[k * 128 + c];
  } else if (t < 73728) {               // W4s: F-permuted, folded over inner i
    int s = t - 69632;
    int j = s & 7, lq = (s >> 3) & 63, kt = (s >> 9) & 3, ct = s >> 11;
    int u = (lq >> 4) & 3;
    int k = kt * 32 + (j >> 2) * 16 + u * 4 + (j & 3), o = ct * 16 + (lq & 15);
    float a = 0.f;
#pragma unroll
    for (int i = 0; i < 32; ++i) a += W4[k * 1024 + o * 32 + i];
    wsh[t] = (f16)a;
  }
  if (t < 32) {
    float a = 0.f;
#pragma unroll
    for (int i = 0; i < 32; ++i) a += b4[t * 32 + i];
    b4r[t] = a;
  }
}

__device__ __forceinline__ uint2 relu_pack(f32x4 a) {
  U32x2 o;
  o.h2[0] = __builtin_amdgcn_cvt_pkrtz(fmaxf(a[0], 0.f), fmaxf(a[1], 0.f));
  o.h2[1] = __builtin_amdgcn_cvt_pkrtz(fmaxf(a[2], 0.f), fmaxf(a[3], 0.f));
  return o.u;
}
__device__ __forceinline__ uint2 bias_relu_pack(f32x4 a, float4 b) {
  U32x2 o;
  o.h2[0] = __builtin_amdgcn_cvt_pkrtz(fmaxf(a[0] + b.x, 0.f), fmaxf(a[1] + b.y, 0.f));
  o.h2[1] = __builtin_amdgcn_cvt_pkrtz(fmaxf(a[2] + b.z, 0.f), fmaxf(a[3] + b.w, 0.f));
  return o.u;
}

// ---------------------------------------------------------------------------
// Fused MLP: 768 threads (12 waves) = 3 waves/SIMD at 1 block/CU. Each wave
// owns 32 edges (2 16-edge tiles; weight frags read once, used twice).
// Activations in VGPRs end-to-end; one barrier (W2s/W3s preload, 128 KB).
// W1/W4 frags from L2. Per-wave guard for the ragged last block.
// ---------------------------------------------------------------------------
__global__ __launch_bounds__(768, 1) void mlp_mfma_kernel(
    const float* __restrict__ e_vw, const float* __restrict__ h_w,
    const float* __restrict__ b2, const float* __restrict__ b3,
    const f16* __restrict__ wsh, const float* __restrict__ b4r,
    float* __restrict__ out) {
  __shared__ f16 WT[65536];   // 128 KB: [0,32768) W2s', [32768,65536) W3s'

  const int tid = threadIdx.x;
  const int l = tid & 63, w = tid >> 6;
  const int e0 = l & 15, u = l >> 4;
  const size_t base = (size_t)blockIdx.x * 384 + (size_t)w * 32;
  const bool active = base < (size_t)131072;

  const f16x8* wp1 = (const f16x8*)(wsh + OFF_W1S);
  const f16x8* wp4 = (const f16x8*)(wsh + OFF_W4S);

  // ---- stage inputs + W1 frags (global; overlaps preload) ----
  U16x8 xin[2];
  f16x8 w1f[8];
  if (active) {
#pragma unroll
    for (int ti = 0; ti < 2; ++ti) {
      if (u < 2) {
        const float* pe = e_vw + (base + ti * 16 + e0) * 16 + u * 8;
        float4 v0 = *reinterpret_cast<const float4*>(pe);
        float4 v1 = *reinterpret_cast<const float4*>(pe + 4);
        U32x2 c0, c1;
        c0.h2[0] = __builtin_amdgcn_cvt_pkrtz(v0.x, v0.y);
        c0.h2[1] = __builtin_amdgcn_cvt_pkrtz(v0.z, v0.w);
        c1.h2[0] = __builtin_amdgcn_cvt_pkrtz(v1.x, v1.y);
        c1.h2[1] = __builtin_amdgcn_cvt_pkrtz(v1.z, v1.w);
        xin[ti].p.lo = c0.u; xin[ti].p.hi = c1.u;
      } else {
        xin[ti].p.lo.x = (u == 2) ? 0x00003C00u : 0u;  // k=16 -> 1.0 (bias)
        xin[ti].p.lo.y = 0u; xin[ti].p.hi.x = 0u; xin[ti].p.hi.y = 0u;
      }
    }
#pragma unroll
    for (int ct = 0; ct < 8; ++ct) w1f[ct] = wp1[ct * 64 + l];
  }

  // ---- preload W2s'/W3s' into LDS (131072 B = 8192 float4, 768 threads) --
  {
    const float4* src = (const float4*)(wsh + OFF_W2S);
    float4* dst = (float4*)WT;
#pragma unroll
    for (int i = 0; i < 11; ++i) {
      int idx = tid + i * 768;
      if (idx < 8192) dst[idx] = src[idx];
    }
  }
  __syncthreads();
  if (!active) return;

  // ---- L1: 16 -> 128 (bias folded in K-pad) ----
  U16x8 x1[2][4];
  const f32x4 z4 = {0.f, 0.f, 0.f, 0.f};
#pragma unroll
  for (int ct = 0; ct < 8; ++ct) {
    f32x4 a0 = __builtin_amdgcn_mfma_f32_16x16x32_f16(w1f[ct], xin[0].v, z4, 0, 0, 0);
    f32x4 a1 = __builtin_amdgcn_mfma_f32_16x16x32_f16(w1f[ct], xin[1].v, z4, 0, 0, 0);
    uint2 d0 = relu_pack(a0), d1 = relu_pack(a1);
    if (ct & 1) { x1[0][ct >> 1].p.hi = d0; x1[1][ct >> 1].p.hi = d1; }
    else        { x1[0][ct >> 1].p.lo = d0; x1[1][ct >> 1].p.lo = d1; }
  }

  // ---- L2: 128 -> 256 (weights from LDS; B-frag = x1[kt] directly) ----
  U16x8 x2[2][8];
#pragma unroll
  for (int ct = 0; ct < 16; ++ct) {
    f32x4 a0 = z4, a1 = z4;
#pragma unroll
    for (int kt = 0; kt < 4; ++kt) {
      f16x8 wf = *(const f16x8*)(WT + ((ct * 4 + kt) * 64 + l) * 8);
      a0 = __builtin_amdgcn_mfma_f32_16x16x32_f16(wf, x1[0][kt].v, a0, 0, 0, 0);
      a1 = __builtin_amdgcn_mfma_f32_16x16x32_f16(wf, x1[1][kt].v, a1, 0, 0, 0);
    }
    float4 bb = *reinterpret_cast<const float4*>(b2 + ct * 16 + u * 4);
    uint2 d0 = bias_relu_pack(a0, bb), d1 = bias_relu_pack(a1, bb);
    if (ct & 1) { x2[0][ct >> 1].p.hi = d0; x2[1][ct >> 1].p.hi = d1; }
    else        { x2[0][ct >> 1].p.lo = d0; x2[1][ct >> 1].p.lo = d1; }
  }

  // ---- L3: 256 -> 128 (weights from LDS) ----
  U16x8 x3[2][4];
#pragma unroll
  for (int ct = 0; ct < 8; ++ct) {
    f32x4 a0 = z4, a1 = z4;
#pragma unroll
    for (int kt = 0; kt < 8; ++kt) {
      f16x8 wf = *(const f16x8*)(WT + 32768 + ((ct * 8 + kt) * 64 + l) * 8);
      a0 = __builtin_amdgcn_mfma_f32_16x16x32_f16(wf, x2[0][kt].v, a0, 0, 0, 0);
      a1 = __builtin_amdgcn_mfma_f32_16x16x32_f16(wf, x2[1][kt].v, a1, 0, 0, 0);
    }
    float4 bb = *reinterpret_cast<const float4*>(b3 + ct * 16 + u * 4);
    uint2 d0 = bias_relu_pack(a0, bb), d1 = bias_relu_pack(a1, bb);
    if (ct & 1) { x3[0][ct >> 1].p.hi = d0; x3[1][ct >> 1].p.hi = d1; }
    else        { x3[0][ct >> 1].p.lo = d0; x3[1][ct >> 1].p.lo = d1; }
  }

  // ---- L4: 128 -> 32 (folded), scale by s_e, coalesced float4 store ----
#pragma unroll
  for (int ti = 0; ti < 2; ++ti) {
    size_t e = base + ti * 16 + e0;
    float s = h_w[(e >> 7) * 32 + ((e & 127) >> 2)];
#pragma unroll
    for (int ct = 0; ct < 2; ++ct) {
      f32x4 acc = z4;
#pragma unroll
      for (int kt = 0; kt < 4; ++kt)
        acc = __builtin_amdgcn_mfma_f32_16x16x32_f16(wp4[(ct * 4 + kt) * 64 + l],
                                                     x3[ti][kt].v, acc, 0, 0, 0);
      float4 bb = *reinterpret_cast<const float4*>(b4r + ct * 16 + u * 4);
      float4 st;
      st.x = s * (acc[0] + bb.x); st.y = s * (acc[1] + bb.y);
      st.z = s * (acc[2] + bb.z); st.w = s * (acc[3] + bb.w);
      *reinterpret_cast<float4*>(out + e * 32 + ct * 16 + u * 4) = st;
    }
  }
}

// ---------------------------------------------------------------------------
extern "C" void kernel_launch(void* const* d_in, const int* in_sizes, int n_in,
                              void* d_out, int out_size, void* d_ws, size_t ws_size,
                              hipStream_t stream) {
  // inputs: h_v, h_w, e_vw, W1, b1, W2, b2, W3, b3, W4, b4
  const float* h_w  = (const float*)d_in[1];
  const float* e_vw = (const float*)d_in[2];
  const float* W1   = (const float*)d_in[3];
  const float* b1   = (const float*)d_in[4];
  const float* W2   = (const float*)d_in[5];
  const float* b2   = (const float*)d_in[6];
  const float* W3   = (const float*)d_in[7];
  const float* b3   = (const float*)d_in[8];
  const float* W4   = (const float*)d_in[9];
  const float* b4   = (const float*)d_in[10];
  float* out = (float*)d_out;

  f16*   wsh = (f16*)d_ws;
  float* b4r = (float*)((char*)d_ws + (size_t)WS_HALFS * 2);

  const int E = in_sizes[2] / 16;            // 131072
  const int blocks = (E + 383) / 384;        // 342 (12 waves x 32 edges)

  hipLaunchKernelGGL(prep_kernel, dim3(288), dim3(256), 0, stream,
                     W1, b1, W2, W3, W4, b4, wsh, b4r);
  hipLaunchKernelGGL(mlp_mfma_kernel, dim3(blocks), dim3(768), 0, stream,
                     e_vw, h_w, b2, b3, wsh, b4r, out);
}